// Round 2
// baseline (1188.231 us; speedup 1.0000x reference)
//
#include <hip/hip_runtime.h>
#include <math.h>

#define BSZ   64
#define TLEN  512
#define ODIM  50000
#define HDIM  2048
#define K1DIM 2560
#define K2DIM 4096
#define KSPLIT 5

typedef __bf16 bf16x8 __attribute__((ext_vector_type(8)));
typedef float f32x4 __attribute__((ext_vector_type(4)));

__device__ __forceinline__ unsigned short f2b(float f) {
    unsigned int u = __float_as_uint(f);
    u += 0x7FFFu + ((u >> 16) & 1u);
    return (unsigned short)(u >> 16);
}

__device__ __forceinline__ bf16x8 ld_bf16x8(const unsigned short* p) {
    union { uint4 u; bf16x8 v; } x;
    x.u = *reinterpret_cast<const uint4*>(p);
    return x.v;
}

// ---------------- K0: build bf16 A matrices ----------------
__global__ __launch_bounds__(256) void prep_kernel(
    const float* __restrict__ enc, const int* __restrict__ ps,
    const float* __restrict__ Et, unsigned short* __restrict__ ctx,
    unsigned short* __restrict__ A2)
{
    int i = blockIdx.x * 256 + threadIdx.x;
    const int NE = BSZ * HDIM;
    if (i < NE) {
        int m = i >> 11, j = i & (HDIM - 1);
        A2[m * K2DIM + HDIM + j] = f2b(enc[i]);
    } else {
        int t = i - NE;
        int m = t / K1DIM, j = t - m * K1DIM;
        int c = j >> 9, e = j & 511;
        int tok = ps[m * 8 + 3 + c];
        ctx[m * K1DIM + j] = f2b(Et[(size_t)tok * 512 + e]);
    }
}

// ---------------- K1: GEMM1 partials: ctx @ W1 ----------------
__global__ __launch_bounds__(256) void gemm1_kernel(
    const unsigned short* __restrict__ Actx, const float* __restrict__ W1,
    float* __restrict__ part)
{
    int n0 = blockIdx.x * 64;
    int ks = blockIdx.y;
    int wave = threadIdx.x >> 6;
    int lane = threadIdx.x & 63;
    int q = lane >> 4, l16 = lane & 15;
    int ncol = n0 + wave * 16 + l16;

    f32x4 acc[4] = {};
    for (int kk = 0; kk < 16; ++kk) {
        int kq = ks * 512 + kk * 32 + q * 8;
        const unsigned short* ap = Actx + l16 * K1DIM + kq;
        bf16x8 a0 = ld_bf16x8(ap);
        bf16x8 a1 = ld_bf16x8(ap + 16 * K1DIM);
        bf16x8 a2 = ld_bf16x8(ap + 32 * K1DIM);
        bf16x8 a3 = ld_bf16x8(ap + 48 * K1DIM);
        const float* wp = W1 + (size_t)kq * HDIM + ncol;
        union { unsigned short s[8]; bf16x8 v; } bb;
#pragma unroll
        for (int j = 0; j < 8; ++j) { bb.s[j] = f2b(*wp); wp += HDIM; }
        acc[0] = __builtin_amdgcn_mfma_f32_16x16x32_bf16(a0, bb.v, acc[0], 0, 0, 0);
        acc[1] = __builtin_amdgcn_mfma_f32_16x16x32_bf16(a1, bb.v, acc[1], 0, 0, 0);
        acc[2] = __builtin_amdgcn_mfma_f32_16x16x32_bf16(a2, bb.v, acc[2], 0, 0, 0);
        acc[3] = __builtin_amdgcn_mfma_f32_16x16x32_bf16(a3, bb.v, acc[3], 0, 0, 0);
    }
    float* pp = part + (size_t)ks * (BSZ * HDIM);
#pragma unroll
    for (int mt = 0; mt < 4; ++mt)
#pragma unroll
        for (int r = 0; r < 4; ++r)
            pp[(mt * 16 + q * 4 + r) * HDIM + ncol] = acc[mt][r];
}

// ---------------- K1b: reduce partials + bias + tanh ----------------
__global__ __launch_bounds__(256) void htanh_kernel(
    const float* __restrict__ part, const float* __restrict__ b1,
    unsigned short* __restrict__ A2)
{
    int i = blockIdx.x * 256 + threadIdx.x;
    int m = i >> 11, n = i & (HDIM - 1);
    float s = b1[n];
#pragma unroll
    for (int ks = 0; ks < KSPLIT; ++ks) s += part[(size_t)ks * (BSZ * HDIM) + m * HDIM + n];
    A2[m * K2DIM + n] = f2b(tanhf(s));
}

// ---------------- K2: big GEMM, LDS-staged W, deep-pipelined ----------------
// N-tile 64, K-tile 64, [k][n] bf16 LDS tile, stride 136 B.
// Pipeline: 2 k-tiles of W prefetched in registers (Sa/Sb), raw s_barrier +
// lgkmcnt(0) only; vmcnt never drained to 0 in the main loop (counted vmcnt(4)).
#define KT 64
#define SKB 136
#define BUFB (KT * SKB)   // 8704 B per buffer

__global__ __launch_bounds__(256) void gemm2_kernel(
    const unsigned short* __restrict__ A, const float* __restrict__ W2,
    const float* __restrict__ W3, const float* __restrict__ b2,
    const float* __restrict__ b3, float* __restrict__ out)
{
    __shared__ char lds[2 * BUFB];
    int bid = blockIdx.x;
    int tile = (bid & 7) * 98 + (bid >> 3);   // XCD-contiguous bands
    if (tile >= 782) return;
    int n0 = tile * 64;

    int tid = threadIdx.x;
    int wave = tid >> 6;
    int lane = tid & 63;
    int q = lane >> 4, l16 = lane & 15;
    int ncol = n0 + wave * 16 + l16;
    int nloc = wave * 16 + l16;

    // staging assignment: rows r*16 + (tid>>4), cols (tid&15)*4
    int rr = tid >> 4;          // 0..15
    int cg = tid & 15;          // col group
    int gcol = n0 + cg * 4;
    if (gcol > ODIM - 4) gcol = ODIM - 4;   // clamp for partial tile 781

    float4 Sa[4], Sb[4];
    f32x4 acc[4] = {};
    const unsigned short* abase = A + l16 * K2DIM;
    char* buf0 = lds;
    char* buf1 = lds + BUFB;

#define ISSUE(S, ktile) do {                                                  \
    int kg0 = (ktile) * KT;                                                   \
    _Pragma("unroll")                                                         \
    for (int r = 0; r < 4; ++r) {                                             \
        int krow = kg0 + r * 16 + rr;                                         \
        const float* srcp = (krow < HDIM) ? (W2 + (size_t)krow * ODIM)        \
                                          : (W3 + (size_t)(krow - HDIM) * ODIM); \
        S[r] = *reinterpret_cast<const float4*>(srcp + gcol);                 \
    } } while (0)

#define CONVERT(S, bufc) do {                                                 \
    _Pragma("unroll")                                                         \
    for (int r = 0; r < 4; ++r) {                                             \
        union { unsigned short s[4]; unsigned long long u; } pk;              \
        pk.s[0] = f2b(S[r].x); pk.s[1] = f2b(S[r].y);                         \
        pk.s[2] = f2b(S[r].z); pk.s[3] = f2b(S[r].w);                         \
        *reinterpret_cast<unsigned long long*>((bufc) + (r * 16 + rr) * SKB + cg * 8) = pk.u; \
    } } while (0)

#define COMPUTE(bufc, ktile) do {                                             \
    _Pragma("unroll")                                                         \
    for (int h = 0; h < 2; ++h) {                                             \
        int kq = (ktile) * KT + h * 32 + q * 8;                               \
        const unsigned short* ap = abase + kq;                                \
        bf16x8 a0 = ld_bf16x8(ap);                                            \
        bf16x8 a1 = ld_bf16x8(ap + 16 * K2DIM);                               \
        bf16x8 a2 = ld_bf16x8(ap + 32 * K2DIM);                               \
        bf16x8 a3 = ld_bf16x8(ap + 48 * K2DIM);                               \
        union { unsigned short s[8]; bf16x8 v; } bb;                          \
        const char* bp = (bufc) + (h * 32 + q * 8) * SKB + nloc * 2;          \
        _Pragma("unroll")                                                     \
        for (int j = 0; j < 8; ++j)                                           \
            bb.s[j] = *reinterpret_cast<const unsigned short*>(bp + j * SKB); \
        acc[0] = __builtin_amdgcn_mfma_f32_16x16x32_bf16(a0, bb.v, acc[0], 0, 0, 0); \
        acc[1] = __builtin_amdgcn_mfma_f32_16x16x32_bf16(a1, bb.v, acc[1], 0, 0, 0); \
        acc[2] = __builtin_amdgcn_mfma_f32_16x16x32_bf16(a2, bb.v, acc[2], 0, 0, 0); \
        acc[3] = __builtin_amdgcn_mfma_f32_16x16x32_bf16(a3, bb.v, acc[3], 0, 0, 0); \
    } } while (0)

#define BARRIER do {                                                          \
    asm volatile("s_waitcnt lgkmcnt(0)" ::: "memory");                        \
    __builtin_amdgcn_s_barrier();                                             \
} while (0)

    // Prologue: tiles 0 and 1 in flight; convert tile 0.
    ISSUE(Sa, 0);
    ISSUE(Sb, 1);
    asm volatile("s_waitcnt vmcnt(4)" ::: "memory");   // tile 0 landed
    CONVERT(Sa, buf0);
    BARRIER;

    // Steady state: tile kt+2 issued, tile kt+1 converted, tile kt computed.
    // vmcnt(4) = the 4 just-issued loads stay in flight across the barrier.
    for (int kt = 0; kt < 62; kt += 2) {
        ISSUE(Sa, kt + 2);
        asm volatile("s_waitcnt vmcnt(4)" ::: "memory");   // tile kt+1 (Sb) landed
        CONVERT(Sb, buf1);
        COMPUTE(buf0, kt);
        BARRIER;

        ISSUE(Sb, kt + 3);
        asm volatile("s_waitcnt vmcnt(4)" ::: "memory");   // tile kt+2 (Sa) landed
        CONVERT(Sa, buf0);
        COMPUTE(buf1, kt + 1);
        BARRIER;
    }
    // Epilogue: tiles 62, 63 (no further prefetch).
    asm volatile("s_waitcnt vmcnt(0)" ::: "memory");       // tile 63 (Sb) landed
    CONVERT(Sb, buf1);
    COMPUTE(buf0, 62);
    BARRIER;
    COMPUTE(buf1, 63);

#undef ISSUE
#undef CONVERT
#undef COMPUTE
#undef BARRIER

    if (ncol < ODIM) {
        float bias = b2[ncol] + b3[ncol];
#pragma unroll
        for (int mt = 0; mt < 4; ++mt)
#pragma unroll
            for (int r = 0; r < 4; ++r)
                out[(size_t)(mt * 16 + q * 4 + r) * ODIM + ncol] = acc[mt][r] + bias;
    }
}

// ---------------- K3: n-gram / reorder features ----------------
__global__ __launch_bounds__(256) void feats_kernel(
    const int* __restrict__ src_g, const int* __restrict__ lens,
    const int* __restrict__ ps, float* __restrict__ out)
{
    __shared__ int src[TLEN];
    int b = blockIdx.x;
    int tid = threadIdx.x;
    for (int t = tid; t < TLEN; t += 256) src[t] = src_g[b * TLEN + t];
    __syncthreads();
    int len = lens[b];
    int w1 = ps[b * 8 + 7];
    int w2a = ps[b * 8 + 6];

    for (int t = tid; t < TLEN; t += 256) {
        int v = src[t];
        bool first = true, big = false, tri = false;
        int kp = TLEN;
        for (int j = 0; j < TLEN; ++j) {
            int sj = src[j];
            int sj1 = (j < TLEN - 1) ? src[j + 1] : -1;
            int sj2 = (j < TLEN - 2) ? src[j + 2] : -1;
            if (j < t && sj == v) first = false;
            if (sj == w1 && sj1 == v) big = true;
            if (sj == w2a && sj1 == w1 && sj2 == v) tri = true;
            if (sj == w1 && j < kp) kp = j;
        }
        if (t < len && first) {
            bool in_list = kp < TLEN;
            bool reo = in_list && (t < kp);
            float add = 0.5f * (1.0f + (big ? 1.0f : 0.0f) + (tri ? 1.0f : 0.0f) + (reo ? 1.0f : 0.0f));
            out[(size_t)b * ODIM + v] += add;
        }
    }
}

// ---------------- K4a: per-row online max/sum ----------------
__global__ __launch_bounds__(256) void rowstats_kernel(
    const float* __restrict__ out, float* __restrict__ stats)
{
    int b = blockIdx.x, tid = threadIdx.x;
    const float* row = out + (size_t)b * ODIM;
    float m = -INFINITY, s = 0.0f;
    for (int i = tid; i < ODIM; i += 256) {
        float x = row[i];
        if (x > m) { s = s * __expf(m - x) + 1.0f; m = x; }
        else s += __expf(x - m);
    }
    __shared__ float ms[256], ss[256];
    ms[tid] = m; ss[tid] = s;
    __syncthreads();
    for (int off = 128; off > 0; off >>= 1) {
        if (tid < off) {
            float m1 = ms[tid], s1 = ss[tid];
            float m2 = ms[tid + off], s2 = ss[tid + off];
            float M = fmaxf(m1, m2);
            ss[tid] = s1 * __expf(m1 - M) + s2 * __expf(m2 - M);
            ms[tid] = M;
        }
        __syncthreads();
    }
    if (tid == 0) { stats[b] = ms[0]; stats[64 + b] = ss[0]; }
}

// ---------------- K4b: in-place normalize ----------------
__global__ __launch_bounds__(256) void norm_kernel(
    float* __restrict__ out, const float* __restrict__ stats)
{
    int i = blockIdx.x * 256 + threadIdx.x;
    int row = i / 12500;
    int off = i - row * 12500;
    float m = stats[row];
    float inv = 1.0f / stats[64 + row];
    float4* p = reinterpret_cast<float4*>(out + (size_t)row * ODIM) + off;
    float4 x = *p;
    x.x = __expf(x.x - m) * inv;
    x.y = __expf(x.y - m) * inv;
    x.z = __expf(x.z - m) * inv;
    x.w = __expf(x.w - m) * inv;
    *p = x;
}

extern "C" void kernel_launch(void* const* d_in, const int* in_sizes, int n_in,
                              void* d_out, int out_size, void* d_ws, size_t ws_size,
                              hipStream_t stream) {
    const float* enc  = (const float*)d_in[0];
    const int*   ps   = (const int*)d_in[1];
    const int*   src  = (const int*)d_in[2];
    const int*   lens = (const int*)d_in[3];
    const float* Et   = (const float*)d_in[4];
    const float* W1   = (const float*)d_in[5];
    const float* b1   = (const float*)d_in[6];
    const float* W2   = (const float*)d_in[7];
    const float* b2   = (const float*)d_in[8];
    const float* W3   = (const float*)d_in[9];
    const float* b3   = (const float*)d_in[10];
    float* out = (float*)d_out;

    char* ws = (char*)d_ws;
    unsigned short* ctx = (unsigned short*)(ws);
    unsigned short* A2  = (unsigned short*)(ws + 524288);
    float* part         = (float*)(ws + 1048576);
    float* stats        = (float*)(ws + 3801088);

    prep_kernel<<<1152, 256, 0, stream>>>(enc, ps, Et, ctx, A2);
    gemm1_kernel<<<dim3(32, KSPLIT), 256, 0, stream>>>(ctx, W1, part);
    htanh_kernel<<<512, 256, 0, stream>>>(part, b1, A2);
    gemm2_kernel<<<784, 256, 0, stream>>>(A2, W2, W3, b2, b3, out);
    feats_kernel<<<64, 256, 0, stream>>>(src, lens, ps, out);
    rowstats_kernel<<<64, 256, 0, stream>>>(out, stats);
    norm_kernel<<<3125, 256, 0, stream>>>(out, stats);
}

// Round 4
// 1041.736 us; speedup vs baseline: 1.1406x; 1.1406x over previous
//
#include <hip/hip_runtime.h>
#include <math.h>

#define BSZ   64
#define TLEN  512
#define ODIM  50000
#define HDIM  2048
#define K1DIM 2560
#define K2DIM 4096
#define KSPLIT 5

typedef __bf16 bf16x8 __attribute__((ext_vector_type(8)));
typedef float f32x4 __attribute__((ext_vector_type(4)));

__device__ __forceinline__ unsigned short f2b(float f) {
    unsigned int u = __float_as_uint(f);
    u += 0x7FFFu + ((u >> 16) & 1u);
    return (unsigned short)(u >> 16);
}

__device__ __forceinline__ bf16x8 ld_bf16x8(const unsigned short* p) {
    union { uint4 u; bf16x8 v; } x;
    x.u = *reinterpret_cast<const uint4*>(p);
    return x.v;
}

// ---------------- K0: build bf16 A matrices ----------------
__global__ __launch_bounds__(256) void prep_kernel(
    const float* __restrict__ enc, const int* __restrict__ ps,
    const float* __restrict__ Et, unsigned short* __restrict__ ctx,
    unsigned short* __restrict__ A2)
{
    int i = blockIdx.x * 256 + threadIdx.x;
    const int NE = BSZ * HDIM;
    if (i < NE) {
        int m = i >> 11, j = i & (HDIM - 1);
        A2[m * K2DIM + HDIM + j] = f2b(enc[i]);
    } else {
        int t = i - NE;
        int m = t / K1DIM, j = t - m * K1DIM;
        int c = j >> 9, e = j & 511;
        int tok = ps[m * 8 + 3 + c];
        ctx[m * K1DIM + j] = f2b(Et[(size_t)tok * 512 + e]);
    }
}

// ---------------- K1: GEMM1 partials: ctx @ W1 ----------------
__global__ __launch_bounds__(256) void gemm1_kernel(
    const unsigned short* __restrict__ Actx, const float* __restrict__ W1,
    float* __restrict__ part)
{
    int n0 = blockIdx.x * 64;
    int ks = blockIdx.y;
    int wave = threadIdx.x >> 6;
    int lane = threadIdx.x & 63;
    int q = lane >> 4, l16 = lane & 15;
    int ncol = n0 + wave * 16 + l16;

    f32x4 acc[4] = {};
    for (int kk = 0; kk < 16; ++kk) {
        int kq = ks * 512 + kk * 32 + q * 8;
        const unsigned short* ap = Actx + l16 * K1DIM + kq;
        bf16x8 a0 = ld_bf16x8(ap);
        bf16x8 a1 = ld_bf16x8(ap + 16 * K1DIM);
        bf16x8 a2 = ld_bf16x8(ap + 32 * K1DIM);
        bf16x8 a3 = ld_bf16x8(ap + 48 * K1DIM);
        const float* wp = W1 + (size_t)kq * HDIM + ncol;
        union { unsigned short s[8]; bf16x8 v; } bb;
#pragma unroll
        for (int j = 0; j < 8; ++j) { bb.s[j] = f2b(*wp); wp += HDIM; }
        acc[0] = __builtin_amdgcn_mfma_f32_16x16x32_bf16(a0, bb.v, acc[0], 0, 0, 0);
        acc[1] = __builtin_amdgcn_mfma_f32_16x16x32_bf16(a1, bb.v, acc[1], 0, 0, 0);
        acc[2] = __builtin_amdgcn_mfma_f32_16x16x32_bf16(a2, bb.v, acc[2], 0, 0, 0);
        acc[3] = __builtin_amdgcn_mfma_f32_16x16x32_bf16(a3, bb.v, acc[3], 0, 0, 0);
    }
    float* pp = part + (size_t)ks * (BSZ * HDIM);
#pragma unroll
    for (int mt = 0; mt < 4; ++mt)
#pragma unroll
        for (int r = 0; r < 4; ++r)
            pp[(mt * 16 + q * 4 + r) * HDIM + ncol] = acc[mt][r];
}

// ---------------- K1b: reduce partials + bias + tanh ----------------
__global__ __launch_bounds__(256) void htanh_kernel(
    const float* __restrict__ part, const float* __restrict__ b1,
    unsigned short* __restrict__ A2)
{
    int i = blockIdx.x * 256 + threadIdx.x;
    int m = i >> 11, n = i & (HDIM - 1);
    float s = b1[n];
#pragma unroll
    for (int ks = 0; ks < KSPLIT; ++ks) s += part[(size_t)ks * (BSZ * HDIM) + m * HDIM + n];
    A2[m * K2DIM + n] = f2b(tanhf(s));
}

// ---------------- K2: big GEMM, BN=128 (512B/row DRAM granule) ----------------
// Diagnosis r2: BN=64 fetched 256B islands at 200KB stride -> ~25% DRAM page
// utilization, 1.24 TB/s. BN=128 doubles per-row contiguity to 512B.
// Pipeline (verified r2): Sa/Sb reg-prefetch 2 tiles ahead, counted vmcnt(8)
// (never 0 in loop), raw s_barrier + lgkmcnt(0) only.
// LDS: [64 rows][264B] bf16. Swizzle: byte XOR 32 on rows with bit4 set
// (involution, stays within the 264B row: cg*8^32 <= 248+32... max 248^32=216,
// all values in 0..255). Reads apply the same XOR -> writes 2-way (free),
// reads 1-way (banks {0,16,8,24}+8-span = all 32).
#define KT 64
#define SKB 264
#define BUFB (KT * SKB)   // 16896 B per buffer

__global__ __launch_bounds__(256) void gemm2_kernel(
    const unsigned short* __restrict__ A, const float* __restrict__ W2,
    const float* __restrict__ W3, const float* __restrict__ b2,
    const float* __restrict__ b3, float* __restrict__ out)
{
    __shared__ char lds[2 * BUFB];
    // bijective XCD swizzle (m204): nwg=391, q=48, r=7
    int bid = blockIdx.x;
    int xcd = bid & 7, idx = bid >> 3;
    int tile = (xcd < 7 ? xcd * 49 : 343) + idx;
    int n0 = tile * 128;

    int tid = threadIdx.x;
    int wave = tid >> 6;
    int lane = tid & 63;
    int q = lane >> 4, l16 = lane & 15;

    // staging: rr = row-in-group (0..7), cg = col group (0..31, 4 cols each)
    int rr = tid >> 5;          // 0..7
    int cg = tid & 31;          // 32 groups x 4 cols = 128 cols
    int gcol = n0 + cg * 4;
    if (gcol > ODIM - 4) gcol = ODIM - 4;   // clamp for partial tile 390

    float4 Sa[8], Sb[8];
    f32x4 acc[4][2] = {};
    const unsigned short* abase = A + l16 * K2DIM;
    char* buf0 = lds;
    char* buf1 = lds + BUFB;

#define ISSUE(S, ktile) do {                                                  \
    int kg0 = (ktile) * KT;                                                   \
    _Pragma("unroll")                                                         \
    for (int r8 = 0; r8 < 8; ++r8) {                                          \
        int krow = kg0 + r8 * 8 + rr;                                         \
        const float* srcp = (krow < HDIM) ? (W2 + (size_t)krow * ODIM)        \
                                          : (W3 + (size_t)(krow - HDIM) * ODIM); \
        S[r8] = *reinterpret_cast<const float4*>(srcp + gcol);                \
    } } while (0)

#define CONVERT(S, bufc) do {                                                 \
    _Pragma("unroll")                                                         \
    for (int r8 = 0; r8 < 8; ++r8) {                                          \
        int row = r8 * 8 + rr;                                                \
        union { unsigned short s[4]; unsigned long long u; } pk;              \
        pk.s[0] = f2b(S[r8].x); pk.s[1] = f2b(S[r8].y);                       \
        pk.s[2] = f2b(S[r8].z); pk.s[3] = f2b(S[r8].w);                       \
        *reinterpret_cast<unsigned long long*>(                               \
            (bufc) + row * SKB + ((cg * 8) ^ ((row & 16) << 1))) = pk.u;      \
    } } while (0)

#define COMPUTE(bufc, ktile) do {                                             \
    _Pragma("unroll")                                                         \
    for (int h = 0; h < 2; ++h) {                                             \
        int kq = (ktile) * KT + h * 32 + q * 8;                               \
        const unsigned short* ap = abase + kq;                                \
        bf16x8 a0 = ld_bf16x8(ap);                                            \
        bf16x8 a1 = ld_bf16x8(ap + 16 * K2DIM);                               \
        bf16x8 a2 = ld_bf16x8(ap + 32 * K2DIM);                               \
        bf16x8 a3 = ld_bf16x8(ap + 48 * K2DIM);                               \
        int rbase = h * 32 + q * 8;                                           \
        const char* bp0 = (bufc) + rbase * SKB;                               \
        int xo = (rbase & 16) << 1;                                           \
        _Pragma("unroll")                                                     \
        for (int sub = 0; sub < 2; ++sub) {                                   \
            union { unsigned short s[8]; bf16x8 v; } bb;                      \
            const char* bp = bp0 + (((wave * 32 + sub * 16 + l16) * 2) ^ xo); \
            _Pragma("unroll")                                                 \
            for (int j = 0; j < 8; ++j)                                       \
                bb.s[j] = *reinterpret_cast<const unsigned short*>(bp + j * SKB); \
            acc[0][sub] = __builtin_amdgcn_mfma_f32_16x16x32_bf16(a0, bb.v, acc[0][sub], 0, 0, 0); \
            acc[1][sub] = __builtin_amdgcn_mfma_f32_16x16x32_bf16(a1, bb.v, acc[1][sub], 0, 0, 0); \
            acc[2][sub] = __builtin_amdgcn_mfma_f32_16x16x32_bf16(a2, bb.v, acc[2][sub], 0, 0, 0); \
            acc[3][sub] = __builtin_amdgcn_mfma_f32_16x16x32_bf16(a3, bb.v, acc[3][sub], 0, 0, 0); \
        }                                                                     \
    } } while (0)

#define BARRIER do {                                                          \
    asm volatile("s_waitcnt lgkmcnt(0)" ::: "memory");                        \
    __builtin_amdgcn_s_barrier();                                             \
} while (0)

    // Prologue: tiles 0 and 1 in flight; convert tile 0.
    ISSUE(Sa, 0);
    ISSUE(Sb, 1);
    asm volatile("s_waitcnt vmcnt(8)" ::: "memory");   // tile 0 landed
    CONVERT(Sa, buf0);
    BARRIER;

    // Steady state: issue kt+2, convert kt+1, compute kt.
    for (int kt = 0; kt < 62; kt += 2) {
        ISSUE(Sa, kt + 2);
        asm volatile("s_waitcnt vmcnt(8)" ::: "memory");   // tile kt+1 (Sb) landed
        CONVERT(Sb, buf1);
        COMPUTE(buf0, kt);
        BARRIER;

        ISSUE(Sb, kt + 3);
        asm volatile("s_waitcnt vmcnt(8)" ::: "memory");   // tile kt+2 (Sa) landed
        CONVERT(Sa, buf0);
        COMPUTE(buf1, kt + 1);
        BARRIER;
    }
    // Epilogue: buf0 holds tile 62 (converted in last loop half).
    asm volatile("s_waitcnt vmcnt(0)" ::: "memory");       // tile 63 (Sb) landed
    CONVERT(Sb, buf1);
    COMPUTE(buf0, 62);
    BARRIER;
    COMPUTE(buf1, 63);

#undef ISSUE
#undef CONVERT
#undef COMPUTE
#undef BARRIER

#pragma unroll
    for (int sub = 0; sub < 2; ++sub) {
        int ncol = n0 + wave * 32 + sub * 16 + l16;
        if (ncol < ODIM) {
            float bias = b2[ncol] + b3[ncol];
#pragma unroll
            for (int mt = 0; mt < 4; ++mt)
#pragma unroll
                for (int r = 0; r < 4; ++r)
                    out[(size_t)(mt * 16 + q * 4 + r) * ODIM + ncol] = acc[mt][sub][r] + bias;
        }
    }
}

// ---------------- K3: n-gram / reorder features ----------------
// 256 blocks (64 b x 4 t-chunks) x 128 threads: one t per thread.
// Race-free across chunks: only the unique first-occurrence t of each v writes.
__global__ __launch_bounds__(128) void feats_kernel(
    const int* __restrict__ src_g, const int* __restrict__ lens,
    const int* __restrict__ ps, float* __restrict__ out)
{
    __shared__ int src[TLEN];
    int b = blockIdx.x >> 2;
    int chunk = blockIdx.x & 3;
    int tid = threadIdx.x;
    for (int t = tid; t < TLEN; t += 128) src[t] = src_g[b * TLEN + t];
    __syncthreads();
    int len = lens[b];
    int w1 = ps[b * 8 + 7];
    int w2a = ps[b * 8 + 6];

    int t = chunk * 128 + tid;
    int v = src[t];
    bool first = true, big = false, tri = false;
    int kp = TLEN;
    for (int j = 0; j < TLEN; ++j) {
        int sj = src[j];
        int sj1 = (j < TLEN - 1) ? src[j + 1] : -1;
        int sj2 = (j < TLEN - 2) ? src[j + 2] : -1;
        if (j < t && sj == v) first = false;
        if (sj == w1 && sj1 == v) big = true;
        if (sj == w2a && sj1 == w1 && sj2 == v) tri = true;
        if (sj == w1 && j < kp) kp = j;
    }
    if (t < len && first) {
        bool in_list = kp < TLEN;
        bool reo = in_list && (t < kp);
        float add = 0.5f * (1.0f + (big ? 1.0f : 0.0f) + (tri ? 1.0f : 0.0f) + (reo ? 1.0f : 0.0f));
        out[(size_t)b * ODIM + v] += add;
    }
}

// ---------------- K4a: per-row online max/sum ----------------
__global__ __launch_bounds__(256) void rowstats_kernel(
    const float* __restrict__ out, float* __restrict__ stats)
{
    int b = blockIdx.x, tid = threadIdx.x;
    const float* row = out + (size_t)b * ODIM;
    float m = -INFINITY, s = 0.0f;
    for (int i = tid; i < ODIM; i += 256) {
        float x = row[i];
        if (x > m) { s = s * __expf(m - x) + 1.0f; m = x; }
        else s += __expf(x - m);
    }
    __shared__ float ms[256], ss[256];
    ms[tid] = m; ss[tid] = s;
    __syncthreads();
    for (int off = 128; off > 0; off >>= 1) {
        if (tid < off) {
            float m1 = ms[tid], s1 = ss[tid];
            float m2 = ms[tid + off], s2 = ss[tid + off];
            float M = fmaxf(m1, m2);
            ss[tid] = s1 * __expf(m1 - M) + s2 * __expf(m2 - M);
            ms[tid] = M;
        }
        __syncthreads();
    }
    if (tid == 0) { stats[b] = ms[0]; stats[64 + b] = ss[0]; }
}

// ---------------- K4b: in-place normalize ----------------
__global__ __launch_bounds__(256) void norm_kernel(
    float* __restrict__ out, const float* __restrict__ stats)
{
    int i = blockIdx.x * 256 + threadIdx.x;
    int row = i / 12500;
    int off = i - row * 12500;
    float m = stats[row];
    float inv = 1.0f / stats[64 + row];
    float4* p = reinterpret_cast<float4*>(out + (size_t)row * ODIM) + off;
    float4 x = *p;
    x.x = __expf(x.x - m) * inv;
    x.y = __expf(x.y - m) * inv;
    x.z = __expf(x.z - m) * inv;
    x.w = __expf(x.w - m) * inv;
    *p = x;
}

extern "C" void kernel_launch(void* const* d_in, const int* in_sizes, int n_in,
                              void* d_out, int out_size, void* d_ws, size_t ws_size,
                              hipStream_t stream) {
    const float* enc  = (const float*)d_in[0];
    const int*   ps   = (const int*)d_in[1];
    const int*   src  = (const int*)d_in[2];
    const int*   lens = (const int*)d_in[3];
    const float* Et   = (const float*)d_in[4];
    const float* W1   = (const float*)d_in[5];
    const float* b1   = (const float*)d_in[6];
    const float* W2   = (const float*)d_in[7];
    const float* b2   = (const float*)d_in[8];
    const float* W3   = (const float*)d_in[9];
    const float* b3   = (const float*)d_in[10];
    float* out = (float*)d_out;

    char* ws = (char*)d_ws;
    unsigned short* ctx = (unsigned short*)(ws);
    unsigned short* A2  = (unsigned short*)(ws + 524288);
    float* part         = (float*)(ws + 1048576);
    float* stats        = (float*)(ws + 3801088);

    prep_kernel<<<1152, 256, 0, stream>>>(enc, ps, Et, ctx, A2);
    gemm1_kernel<<<dim3(32, KSPLIT), 256, 0, stream>>>(ctx, W1, part);
    htanh_kernel<<<512, 256, 0, stream>>>(part, b1, A2);
    gemm2_kernel<<<391, 256, 0, stream>>>(A2, W2, W3, b2, b3, out);
    feats_kernel<<<256, 128, 0, stream>>>(src, lens, ps, out);
    rowstats_kernel<<<64, 256, 0, stream>>>(out, stats);
    norm_kernel<<<3125, 256, 0, stream>>>(out, stats);
}